// Round 7
// baseline (853.861 us; speedup 1.0000x reference)
//
#include <hip/hip_runtime.h>

#define BB 8
#define TT 4096
#define CC 512
#define NCHUNK 128
#define LCHUNK (TT / NCHUNK)   // 32
#define NL (CC / 2)            // 256 float4 lanes per (b,t) row
#define WB 16                  // prefix-walk batch width (pipelined loads)
#define AGG_MAGIC 0x5EC7A9B1u  // cannot alias typical poison patterns

typedef float floatx4 __attribute__((ext_vector_type(4)));

// Single-launch chained scan. Block (b, chunk j) with chunk-major dispatch
// (b = blk % BB) so predecessor chunks launch first. Steps:
//  1. Stream x tile, local scan with zero init -> E_j (chunk aggregate).
//  2. Publish E_j per-lane into ws: payload store, __threadfence (agent
//     release: wbL2), then agent-scope atomic flag store. Publication is
//     UNCONDITIONAL and happens before any wait -> no circular dependency.
//  3. Resolve prefix: for k = j-1..0 in 16-wide batches: batch-load flags
//     (agent atomic, L1-bypassed, pipelined), verify, one acquire fence
//     (invalidates L1/L2), batch-load payloads (pipelined), accumulate
//     acc += P*E_k, P *= A^L. Addresses independent -> full MLP, no serial
//     memory chain. S_start = acc + P*h0.
//  4. Emit 32 steps (x re-read, L3-hot) with nontemporal stores.
// Co-residency: __launch_bounds__(256,4) caps VGPR<=128 -> 4 blocks/CU
// x 256 CU = all 1024 blocks resident; spin cannot starve.
__global__ __launch_bounds__(256, 4) void rec_onepass(
    const float* __restrict__ x,
    const float* __restrict__ Ar,
    const float* __restrict__ Ai,
    const float* __restrict__ h0r,
    const float* __restrict__ h0i,
    float4* __restrict__ pay,
    unsigned* __restrict__ flg,
    float4* __restrict__ out)
{
    const int tid = threadIdx.x;           // channels 2*tid, 2*tid+1
    const int blk = blockIdx.x;
    const int b   = blk % BB;              // chunk-major: low chunks first
    const int j   = blk / BB;
    const int t0  = j * LCHUNK;

    const float2 a_r = ((const float2*)Ar)[tid];
    const float2 a_i = ((const float2*)Ai)[tid];
    const float2* xp = (const float2*)(x + (size_t)(b * TT + t0) * CC) + tid;

    // ---- 1. local scan (streaming, loads pipelined by unroll) ----
    float hr0 = 0.f, hi0 = 0.f, hr1 = 0.f, hi1 = 0.f;
#pragma unroll 8
    for (int t = 0; t < LCHUNK; ++t) {
        float2 xv = xp[(size_t)t * NL];
        float nr0 = fmaf(hr0, a_r.x, fmaf(-hi0, a_i.x, xv.x));
        float ni0 = fmaf(a_i.x, hr0, a_r.x * hi0);
        float nr1 = fmaf(hr1, a_r.y, fmaf(-hi1, a_i.y, xv.y));
        float ni1 = fmaf(a_i.y, hr1, a_r.y * hi1);
        hr0 = nr0; hi0 = ni0; hr1 = nr1; hi1 = ni1;
    }

    // ---- 2. publish aggregate (not needed for last chunk) ----
    if (j < NCHUNK - 1) {
        pay[(size_t)blk * NL + tid] = make_float4(hr0, hi0, hr1, hi1);
        __threadfence();   // agent release: payload visible device-wide
        __hip_atomic_store(&flg[(size_t)blk * NL + tid], AGG_MAGIC,
                           __ATOMIC_RELAXED, __HIP_MEMORY_SCOPE_AGENT);
    }

    // A^LCHUNK per channel (5 complex squarings)
    float q0r = a_r.x, q0i = a_i.x, q1r = a_r.y, q1i = a_i.y;
#pragma unroll
    for (int s = 0; s < 5; ++s) {
        float n0r = q0r * q0r - q0i * q0i, n0i = 2.f * q0r * q0i;
        float n1r = q1r * q1r - q1i * q1i, n1i = 2.f * q1r * q1i;
        q0r = n0r; q0i = n0i; q1r = n1r; q1i = n1i;
    }

    const float2 h0rv = ((const float2*)(h0r + (size_t)b * CC))[tid];
    const float2 h0iv = ((const float2*)(h0i + (size_t)b * CC))[tid];

    // ---- 3. prefix walk: acc = sum A^{L(j-1-k)} E_k, then + A^{Lj} h0 ----
    float ar0 = 0.f, ai0 = 0.f, ar1 = 0.f, ai1 = 0.f;   // acc
    float pr0 = 1.f, pi0 = 0.f, pr1 = 1.f, pi1 = 0.f;   // P = (A^L)^hops
    for (int i0 = j - 1; i0 >= 0; i0 -= WB) {
        unsigned fl[WB];
        bool ok;
        do {
            ok = true;
#pragma unroll
            for (int i = 0; i < WB; ++i) {
                const int k = i0 - i;
                fl[i] = (k >= 0)
                    ? __hip_atomic_load(&flg[(size_t)(k * BB + b) * NL + tid],
                                        __ATOMIC_RELAXED, __HIP_MEMORY_SCOPE_AGENT)
                    : AGG_MAGIC;
                ok = ok && (fl[i] == AGG_MAGIC);
            }
            if (!ok) __builtin_amdgcn_s_sleep(2);
        } while (!ok);
        __threadfence();   // acquire: payload reads below see fresh data
#pragma unroll
        for (int i = 0; i < WB; ++i) {
            const int k = i0 - i;                 // block-uniform -> no diverge
            if (k >= 0) {
                float4 e = pay[(size_t)(k * BB + b) * NL + tid];
                ar0 += pr0 * e.x - pi0 * e.y;  ai0 += pi0 * e.x + pr0 * e.y;
                ar1 += pr1 * e.z - pi1 * e.w;  ai1 += pi1 * e.z + pr1 * e.w;
                float t0r = pr0 * q0r - pi0 * q0i, t0i = pr0 * q0i + pi0 * q0r;
                float t1r = pr1 * q1r - pi1 * q1i, t1i = pr1 * q1i + pi1 * q1r;
                pr0 = t0r; pi0 = t0i; pr1 = t1r; pi1 = t1i;
            }
        }
    }
    float sr0 = ar0 + pr0 * h0rv.x - pi0 * h0iv.x;
    float si0 = ai0 + pi0 * h0rv.x + pr0 * h0iv.x;
    float sr1 = ar1 + pr1 * h0rv.y - pi1 * h0iv.y;
    float si1 = ai1 + pi1 * h0rv.y + pr1 * h0iv.y;

    // ---- 4. emit 32 steps (x re-read, L2/L3-hot), NT stores ----
    hr0 = sr0; hi0 = si0; hr1 = sr1; hi1 = si1;
    floatx4* op = (floatx4*)(out + (size_t)(b * TT + t0) * NL + tid);
#pragma unroll 8
    for (int t = 0; t < LCHUNK; ++t) {
        float2 xv = xp[(size_t)t * NL];
        float nr0 = fmaf(hr0, a_r.x, fmaf(-hi0, a_i.x, xv.x));
        float ni0 = fmaf(a_i.x, hr0, a_r.x * hi0);
        float nr1 = fmaf(hr1, a_r.y, fmaf(-hi1, a_i.y, xv.y));
        float ni1 = fmaf(a_i.y, hr1, a_r.y * hi1);
        hr0 = nr0; hi0 = ni0; hr1 = nr1; hi1 = ni1;
        floatx4 v = {nr0, ni0, nr1, ni1};
        __builtin_nontemporal_store(v, &op[(size_t)t * NL]);
    }
}

extern "C" void kernel_launch(void* const* d_in, const int* in_sizes, int n_in,
                              void* d_out, int out_size, void* d_ws, size_t ws_size,
                              hipStream_t stream) {
    const float* x   = (const float*)d_in[0];
    const float* Ar  = (const float*)d_in[1];
    const float* Ai  = (const float*)d_in[2];
    const float* h0r = (const float*)d_in[3];
    const float* h0i = (const float*)d_in[4];
    float4*   pay = (float4*)d_ws;                            // 4 MiB
    unsigned* flg = (unsigned*)((char*)d_ws + (8u << 20));    // 1 MiB @ +8 MiB
    float4*   out = (float4*)d_out;

    rec_onepass<<<BB * NCHUNK, 256, 0, stream>>>(x, Ar, Ai, h0r, h0i,
                                                 pay, flg, out);
}

// Round 8
// 208.695 us; speedup vs baseline: 4.0914x; 4.0914x over previous
//
#include <hip/hip_runtime.h>

#define BB 8
#define TT 4096
#define CC 512
#define NCHUNK 128
#define LCHUNK (TT / NCHUNK)   // 32

typedef float floatx4 __attribute__((ext_vector_type(4)));

// Kernel 1: per-chunk local scan with zero initial state; store chunk-end
// state (float4 = 2 channels' r,i), layout [chunk][b][c/2]. Pure streaming
// HBM read -> run at max occupancy (8 waves/EU, VGPR<=64).
__global__ __launch_bounds__(256, 8) void rec_ends(const float* __restrict__ x,
                                                   const float* __restrict__ Ar,
                                                   const float* __restrict__ Ai,
                                                   float4* __restrict__ s_end) {
    const int tid   = threadIdx.x;            // channels 2*tid, 2*tid+1
    const int blk   = blockIdx.x;
    const int b     = blk / NCHUNK;
    const int chunk = blk % NCHUNK;
    const int t0    = chunk * LCHUNK;

    const float2 a_r = ((const float2*)Ar)[tid];
    const float2 a_i = ((const float2*)Ai)[tid];
    const float2* xp = (const float2*)(x + (size_t)(b * TT + t0) * CC) + tid;

    float hr0 = 0.f, hi0 = 0.f, hr1 = 0.f, hi1 = 0.f;
#pragma unroll 8
    for (int t = 0; t < LCHUNK; ++t) {
        float2 xv = xp[(size_t)t * (CC / 2)];
        float nr0 = fmaf(hr0, a_r.x, fmaf(-hi0, a_i.x, xv.x));
        float ni0 = fmaf(a_i.x, hr0, a_r.x * hi0);
        float nr1 = fmaf(hr1, a_r.y, fmaf(-hi1, a_i.y, xv.y));
        float ni1 = fmaf(a_i.y, hr1, a_r.y * hi1);
        hr0 = nr0; hi0 = ni0; hr1 = nr1; hi1 = ni1;
    }
    s_end[(size_t)(chunk * BB + b) * (CC / 2) + tid] = make_float4(hr0, hi0, hr1, hi1);
}

// Kernel 2: stage x in registers (overlaps the prefix chain), compute own
// chunk-start via A^L prefix over earlier chunks' end-states (L2/L3-resident,
// independent addresses, 8 loads in flight), then emit all 32 steps with
// nontemporal stores (out never pollutes L2).
__global__ __launch_bounds__(256, 4) void rec_emit(const float* __restrict__ x,
                                                   const float* __restrict__ Ar,
                                                   const float* __restrict__ Ai,
                                                   const float* __restrict__ h0r,
                                                   const float* __restrict__ h0i,
                                                   const float4* __restrict__ s_end,
                                                   float4* __restrict__ out) {
    const int tid   = threadIdx.x;
    const int blk   = blockIdx.x;
    const int b     = blk / NCHUNK;
    const int chunk = blk % NCHUNK;
    const int t0    = chunk * LCHUNK;

    const float2 a_r = ((const float2*)Ar)[tid];
    const float2 a_i = ((const float2*)Ai)[tid];

    // Issue x loads FIRST; they stay in flight while the prefix chain runs.
    const float2* xp = (const float2*)(x + (size_t)(b * TT + t0) * CC) + tid;
    float2 xs[LCHUNK];
#pragma unroll
    for (int t = 0; t < LCHUNK; ++t)
        xs[t] = xp[(size_t)t * (CC / 2)];

    // A^LCHUNK per channel (LCHUNK = 32 -> 5 complex squarings).
    float p0r = a_r.x, p0i = a_i.x, p1r = a_r.y, p1i = a_i.y;
#pragma unroll
    for (int s = 0; s < 5; ++s) {
        float n0r = p0r * p0r - p0i * p0i, n0i = 2.f * p0r * p0i;
        float n1r = p1r * p1r - p1i * p1i, n1i = 2.f * p1r * p1i;
        p0r = n0r; p0i = n0i; p1r = n1r; p1i = n1i;
    }

    // Chunk-start state: h = h0; for j<chunk: h = A^L*h + s_end[j].
    float2 h0rv = ((const float2*)(h0r + (size_t)b * CC))[tid];
    float2 h0iv = ((const float2*)(h0i + (size_t)b * CC))[tid];
    float hr0 = h0rv.x, hr1 = h0rv.y, hi0 = h0iv.x, hi1 = h0iv.y;

    const float4* sp = s_end + tid;
#pragma unroll 8
    for (int j = 0; j < chunk; ++j) {
        float4 s = sp[(size_t)(j * BB + b) * (CC / 2)];
        float nr0 = p0r * hr0 - p0i * hi0 + s.x;
        float ni0 = p0i * hr0 + p0r * hi0 + s.y;
        float nr1 = p1r * hr1 - p1i * hi1 + s.z;
        float ni1 = p1i * hr1 + p1r * hi1 + s.w;
        hr0 = nr0; hi0 = ni0; hr1 = nr1; hi1 = ni1;
    }

    // Emit all 32 steps from register-staged x; streaming stores.
    floatx4* op = (floatx4*)(out + (size_t)(b * TT + t0) * (CC / 2) + tid);
#pragma unroll
    for (int t = 0; t < LCHUNK; ++t) {
        float2 xv = xs[t];
        float nr0 = fmaf(hr0, a_r.x, fmaf(-hi0, a_i.x, xv.x));
        float ni0 = fmaf(a_i.x, hr0, a_r.x * hi0);
        float nr1 = fmaf(hr1, a_r.y, fmaf(-hi1, a_i.y, xv.y));
        float ni1 = fmaf(a_i.y, hr1, a_r.y * hi1);
        hr0 = nr0; hi0 = ni0; hr1 = nr1; hi1 = ni1;
        floatx4 v = {nr0, ni0, nr1, ni1};
        __builtin_nontemporal_store(v, &op[(size_t)t * (CC / 2)]);
    }
}

extern "C" void kernel_launch(void* const* d_in, const int* in_sizes, int n_in,
                              void* d_out, int out_size, void* d_ws, size_t ws_size,
                              hipStream_t stream) {
    const float* x   = (const float*)d_in[0];
    const float* Ar  = (const float*)d_in[1];
    const float* Ai  = (const float*)d_in[2];
    const float* h0r = (const float*)d_in[3];
    const float* h0i = (const float*)d_in[4];
    float4* s_end = (float4*)d_ws;          // NCHUNK*BB*(CC/2) float4 = 4 MiB

    rec_ends<<<BB * NCHUNK, 256, 0, stream>>>(x, Ar, Ai, s_end);
    rec_emit<<<BB * NCHUNK, 256, 0, stream>>>(x, Ar, Ai, h0r, h0i, s_end,
                                              (float4*)d_out);
}